// Round 14
// baseline (219.869 us; speedup 1.0000x reference)
//
#include <hip/hip_runtime.h>
#include <cstdint>

#define NODES 50000
#define FIN   128
#define C1    128   // HEADS*HID
#define HEADS 4
#define HID   32
#define CLS   40
#define SLOPE 0.2f

#define NBUCK ((NODES + 255) >> 8)   // 196
#define EPB 2048                     // edges per bucketA block
#define BCAP 8192                    // fixed bucket capacity (max actual ~4.3k)

__device__ __forceinline__ float lrelu(float v) { return v > 0.f ? v : SLOPE * v; }

__device__ __forceinline__ unsigned short f2bf(float f) {
    union { float f; unsigned u; } v; v.f = f;
    unsigned u = v.u;
    return (unsigned short)((u + 0x7FFFu + ((u >> 16) & 1u)) >> 16);
}
__device__ __forceinline__ float bf2f(unsigned short b) {
    union { unsigned u; float f; } v; v.u = ((unsigned)b) << 16;
    return v.f;
}
__device__ __forceinline__ float bflo(unsigned u) {
    union { unsigned x; float f; } v; v.x = u << 16; return v.f;
}
__device__ __forceinline__ float bfhi(unsigned u) {
    union { unsigned x; float f; } v; v.x = u & 0xffff0000u; return v.f;
}

typedef __attribute__((ext_vector_type(8))) short bf16x8;
typedef __attribute__((ext_vector_type(4))) float f32x4;
typedef __attribute__((ext_vector_type(4), aligned(4))) int int4a;
typedef __attribute__((ext_vector_type(2), aligned(4))) int int2a;

union BF8 { uint4 u; bf16x8 v; };

// ---- prep: W1->bf16 transposed (LDS-coalesced), W2->bf16 transposed, bwp init ----
__global__ __launch_bounds__(256) void k_prep(const float* __restrict__ W1,
                                              const float* __restrict__ W2,
                                              unsigned short* __restrict__ w1t,
                                              unsigned short* __restrict__ w2t,
                                              int* __restrict__ bwp) {
    __shared__ unsigned short Tb[128][136];
    const int t = threadIdx.x;
#pragma unroll
    for (int i = 0; i < 64; i++) {
        int p = i * 256 + t;
        int k = p >> 7, n = p & 127;
        Tb[n][k] = f2bf(W1[(size_t)k * C1 + n]);
    }
    __syncthreads();
#pragma unroll
    for (int i = 0; i < 8; i++) {
        int p = i * 256 + t;
        int n = p >> 4, k8 = (p & 15) * 8;
        *(uint4*)(w1t + n * 128 + k8) = *(uint4*)(&Tb[n][k8]);
    }
    for (int p = t; p < CLS * 128; p += 256) {
        int n = p >> 7, k = p & 127;
        w2t[n * 128 + k] = f2bf(W2[(size_t)k * CLS + n]);
    }
    if (t < NBUCK) bwp[t] = t * BCAP;
}

// ---- front: blocks [0,GB1) = GEMM1 (MFMA bf16 + fused att1);
//             blocks [GB1,..) = bucketA (independent inputs/outputs) ----
__global__ __launch_bounds__(256) void k_front(const float* __restrict__ X,
                                               const unsigned short* __restrict__ w1t,
                                               const float* __restrict__ AS,
                                               const float* __restrict__ AD,
                                               unsigned short* __restrict__ h1b,
                                               float* __restrict__ as1,
                                               float* __restrict__ ad1,
                                               const int* __restrict__ src,
                                               const int* __restrict__ dst, int E,
                                               int* __restrict__ bwp,
                                               int* __restrict__ tmp, int GB1) {
    __shared__ unsigned short Asm[64][136];
    __shared__ unsigned short Wt[128][136];
    __shared__ int cnt[NBUCK];
    __shared__ int bbs[NBUCK];
    const int t = threadIdx.x;

    if (blockIdx.x >= GB1) {
        // ---------------- bucketA body ----------------
        for (int i = t; i < NBUCK; i += 256) cnt[i] = 0;
        __syncthreads();
        const int e0 = (blockIdx.x - GB1) * EPB;
        int v[8], rb[8];
#pragma unroll
        for (int k = 0; k < 8; k++) {
            int e = e0 + k * 256 + t;
            rb[k] = -1;
            if (e < E) {
                int d = dst[e], s = src[e];
                int b = d >> 8;
                int r = atomicAdd(&cnt[b], 1);
                v[k] = (s << 8) | (d & 255);
                rb[k] = (r << 8) | b;
            }
        }
        __syncthreads();
        for (int i = t; i < NBUCK; i += 256) {
            int c = cnt[i];
            bbs[i] = c ? atomicAdd(&bwp[i], c) : 0;
        }
        __syncthreads();
#pragma unroll
        for (int k = 0; k < 8; k++) {
            if (rb[k] >= 0) {
                int b = rb[k] & 255;
                int r = rb[k] >> 8;
                tmp[bbs[b] + r] = v[k];
            }
        }
        return;
    }

    // ---------------- GEMM1 body ----------------
    const int row0 = blockIdx.x * 64;
#pragma unroll
    for (int i = 0; i < 8; i++) {
        int p = i * 256 + t;
        int n = p >> 4, k8 = (p & 15) * 8;
        *(uint4*)(&Wt[n][k8]) = *(const uint4*)(w1t + n * 128 + k8);
    }
    {
        int r = t >> 2, c0 = (t & 3) * 32;
        int gr = row0 + r;
        unsigned short tb[32];
        if (gr < NODES) {
#pragma unroll
            for (int i = 0; i < 8; i++) {
                float4 v = *(const float4*)(X + (size_t)gr * FIN + c0 + i * 4);
                tb[i * 4 + 0] = f2bf(v.x); tb[i * 4 + 1] = f2bf(v.y);
                tb[i * 4 + 2] = f2bf(v.z); tb[i * 4 + 3] = f2bf(v.w);
            }
        } else {
#pragma unroll
            for (int i = 0; i < 32; i++) tb[i] = 0;
        }
#pragma unroll
        for (int i = 0; i < 4; i++) {
            uint4 pk;
            pk.x = (unsigned)tb[i*8+0] | ((unsigned)tb[i*8+1] << 16);
            pk.y = (unsigned)tb[i*8+2] | ((unsigned)tb[i*8+3] << 16);
            pk.z = (unsigned)tb[i*8+4] | ((unsigned)tb[i*8+5] << 16);
            pk.w = (unsigned)tb[i*8+6] | ((unsigned)tb[i*8+7] << 16);
            *(uint4*)(&Asm[r][c0 + i * 8]) = pk;
        }
    }
    __syncthreads();

    const int w = t >> 6, l = t & 63;
    const int lm = l & 15, quad = l >> 4;
    f32x4 acc[8];
#pragma unroll
    for (int ct = 0; ct < 8; ct++) acc[ct] = (f32x4){0.f, 0.f, 0.f, 0.f};
#pragma unroll
    for (int kt = 0; kt < 4; kt++) {
        bf16x8 a = *(const bf16x8*)(&Asm[w * 16 + lm][kt * 32 + quad * 8]);
#pragma unroll
        for (int ct = 0; ct < 8; ct++) {
            bf16x8 b = *(const bf16x8*)(&Wt[ct * 16 + lm][kt * 32 + quad * 8]);
            acc[ct] = __builtin_amdgcn_mfma_f32_16x16x32_bf16(a, b, acc[ct], 0, 0, 0);
        }
    }
    __syncthreads();
#pragma unroll
    for (int ct = 0; ct < 8; ct++)
#pragma unroll
        for (int r = 0; r < 4; r++)
            Asm[w * 16 + quad * 4 + r][ct * 16 + lm] = f2bf(acc[ct][r]);
    __syncthreads();
    {
        int r = t >> 2, c0 = (t & 3) * 32;
        int gr = row0 + r;
        if (gr < NODES) {
#pragma unroll
            for (int i = 0; i < 4; i++)
                *(uint4*)(h1b + (size_t)gr * C1 + c0 + i * 8) =
                    *(uint4*)(&Asm[r][c0 + i * 8]);
        }
    }
    {
        int r = t >> 2, h = t & 3;
        int gr = row0 + r;
        if (gr < NODES) {
            float s = 0.f, d = 0.f;
#pragma unroll
            for (int j = 0; j < 32; j++) {
                float v = bf2f(Asm[r][h * 32 + j]);
                s = fmaf(v, AS[h * HID + j], s);
                d = fmaf(v, AD[h * HID + j], d);
            }
            as1[gr * HEADS + h] = s;
            ad1[gr * HEADS + h] = d;
        }
    }
}

// ---- pass B: per-bucket degree+scan -> rowptr/deg, scatter col ----
__global__ __launch_bounds__(256) void k_bucketB(const int* __restrict__ bwp,
                                                 const int* __restrict__ tmp,
                                                 int* __restrict__ col,
                                                 int* __restrict__ rowptr,
                                                 int* __restrict__ degarr) {
    __shared__ int degs[256];
    __shared__ int wp[256];
    __shared__ int wsum[4];
    const int b = blockIdx.x, t = threadIdx.x;
    const int n0 = b << 8;
    const int beg = b * BCAP;
    const int end = bwp[b];
    degs[t] = 0;
    __syncthreads();
    for (int e = beg + t; e < end; e += 256)
        atomicAdd(&degs[tmp[e] & 255], 1);
    __syncthreads();
    const int d = degs[t];
    int incl = d;
    const int lane = t & 63, w = t >> 6;
#pragma unroll
    for (int s = 1; s < 64; s <<= 1) {
        int u = __shfl_up(incl, s);
        if (lane >= s) incl += u;
    }
    if (lane == 63) wsum[w] = incl;
    __syncthreads();
    if (t == 0) {
        int r = 0;
#pragma unroll
        for (int i = 0; i < 4; i++) { int x = wsum[i]; wsum[i] = r; r += x; }
    }
    __syncthreads();
    const int excl = incl - d + wsum[w] + beg;
    const int nidx = n0 + t;
    if (nidx < NODES) { rowptr[nidx] = excl; degarr[nidx] = d; }
    wp[t] = excl;
    __syncthreads();
    for (int e = beg + t; e < end; e += 256) {
        int v = tmp[e];
        int p = atomicAdd(&wp[v & 255], 1);
        col[p] = v >> 8;
    }
}

// ---- layer-1 aggregation + FUSED GEMM2/att2: one wave per dst node ----
// Edge loop as before (inline weights, 4 gather chains). Epilogue: the wave's
// out1 row (all lanes hold full sums after xor-reduce) is multiplied by W2
// via 12 mfma_16x16x32_bf16 (A = row in lanes ll==0, built by shfl; B from
// LDS-staged Wt2; C row 0 -> lanes 0..15 reg 0). Writes h2b + as2/ad2.
__global__ __launch_bounds__(256) void k_agg1(const unsigned short* __restrict__ h1b,
                                              const float* __restrict__ as1,
                                              const float* __restrict__ ad1,
                                              const int* __restrict__ rowptr,
                                              const int* __restrict__ degarr,
                                              const int* __restrict__ col,
                                              const float* __restrict__ b1,
                                              const unsigned short* __restrict__ w2t,
                                              const float* __restrict__ AS2,
                                              const float* __restrict__ AD2,
                                              unsigned short* __restrict__ h2b,
                                              float* __restrict__ as2,
                                              float* __restrict__ ad2) {
    __shared__ unsigned short Wt2[48][136];
    const int t = threadIdx.x;
    // stage W2 (bf16, rows 0..39) + zero pad rows 40..47
    for (int p = t; p < 640; p += 256) {
        int nn = p >> 4, k8 = (p & 15) * 8;
        *(uint4*)(&Wt2[nn][k8]) = *(const uint4*)(w2t + nn * 128 + k8);
    }
    for (int p = t; p < 8 * 136; p += 256) Wt2[40 + p / 136][p % 136] = 0;
    __syncthreads();

    int wid = (blockIdx.x * 256 + t) >> 6;     // grid is exactly NODES waves
    const int lane = t & 63;
    const int q  = lane >> 4;       // edge slot / MFMA quad
    const int ll = lane & 15;       // channel group / MFMA lane-m
    const int fh = ll >> 2;         // head
    const int n = wid;
    const float adn = ad1[n * HEADS + fh];
    const int rs = rowptr[n];
    const int re = rs + degarr[n];

    float den = 0.f;
    float ac[8];
#pragma unroll
    for (int k = 0; k < 8; k++) ac[k] = 0.f;

    int base = rs;
    for (; base + 16 <= re; base += 16) {
        int4a cc = *(const int4a*)(col + base + q * 4);
        float w0 = __expf(lrelu(as1[cc.x * HEADS + fh] + adn));
        float w1 = __expf(lrelu(as1[cc.y * HEADS + fh] + adn));
        float w2 = __expf(lrelu(as1[cc.z * HEADS + fh] + adn));
        float w3 = __expf(lrelu(as1[cc.w * HEADS + fh] + adn));
        den += (w0 + w1) + (w2 + w3);
        uint4 p0 = *(const uint4*)((const char*)h1b + (((unsigned)cc.x << 8) + (unsigned)(ll << 4)));
        uint4 p1 = *(const uint4*)((const char*)h1b + (((unsigned)cc.y << 8) + (unsigned)(ll << 4)));
        uint4 p2 = *(const uint4*)((const char*)h1b + (((unsigned)cc.z << 8) + (unsigned)(ll << 4)));
        uint4 p3 = *(const uint4*)((const char*)h1b + (((unsigned)cc.w << 8) + (unsigned)(ll << 4)));
        ac[0] = fmaf(w0, bflo(p0.x), ac[0]); ac[1] = fmaf(w0, bfhi(p0.x), ac[1]);
        ac[2] = fmaf(w0, bflo(p0.y), ac[2]); ac[3] = fmaf(w0, bfhi(p0.y), ac[3]);
        ac[4] = fmaf(w0, bflo(p0.z), ac[4]); ac[5] = fmaf(w0, bfhi(p0.z), ac[5]);
        ac[6] = fmaf(w0, bflo(p0.w), ac[6]); ac[7] = fmaf(w0, bfhi(p0.w), ac[7]);
        ac[0] = fmaf(w1, bflo(p1.x), ac[0]); ac[1] = fmaf(w1, bfhi(p1.x), ac[1]);
        ac[2] = fmaf(w1, bflo(p1.y), ac[2]); ac[3] = fmaf(w1, bfhi(p1.y), ac[3]);
        ac[4] = fmaf(w1, bflo(p1.z), ac[4]); ac[5] = fmaf(w1, bfhi(p1.z), ac[5]);
        ac[6] = fmaf(w1, bflo(p1.w), ac[6]); ac[7] = fmaf(w1, bfhi(p1.w), ac[7]);
        ac[0] = fmaf(w2, bflo(p2.x), ac[0]); ac[1] = fmaf(w2, bfhi(p2.x), ac[1]);
        ac[2] = fmaf(w2, bflo(p2.y), ac[2]); ac[3] = fmaf(w2, bfhi(p2.y), ac[3]);
        ac[4] = fmaf(w2, bflo(p2.z), ac[4]); ac[5] = fmaf(w2, bfhi(p2.z), ac[5]);
        ac[6] = fmaf(w2, bflo(p2.w), ac[6]); ac[7] = fmaf(w2, bfhi(p2.w), ac[7]);
        ac[0] = fmaf(w3, bflo(p3.x), ac[0]); ac[1] = fmaf(w3, bfhi(p3.x), ac[1]);
        ac[2] = fmaf(w3, bflo(p3.y), ac[2]); ac[3] = fmaf(w3, bfhi(p3.y), ac[3]);
        ac[4] = fmaf(w3, bflo(p3.z), ac[4]); ac[5] = fmaf(w3, bfhi(p3.z), ac[5]);
        ac[6] = fmaf(w3, bflo(p3.w), ac[6]); ac[7] = fmaf(w3, bfhi(p3.w), ac[7]);
    }
    for (; base < re; base += 4) {
        int i = base + q;
        int c = (i < re) ? col[i] : n;
        float w = __expf(lrelu(as1[c * HEADS + fh] + adn));
        if (i >= re) w = 0.f;
        den += w;
        unsigned off = ((unsigned)c << 8) + (unsigned)(ll << 4);
        uint4 pk = *(const uint4*)((const char*)h1b + off);
        ac[0] = fmaf(w, bflo(pk.x), ac[0]); ac[1] = fmaf(w, bfhi(pk.x), ac[1]);
        ac[2] = fmaf(w, bflo(pk.y), ac[2]); ac[3] = fmaf(w, bfhi(pk.y), ac[3]);
        ac[4] = fmaf(w, bflo(pk.z), ac[4]); ac[5] = fmaf(w, bfhi(pk.z), ac[5]);
        ac[6] = fmaf(w, bflo(pk.w), ac[6]); ac[7] = fmaf(w, bfhi(pk.w), ac[7]);
    }
    // reduce across edge slots q (lane bits 4,5) -> ALL lanes hold full sums
    den += __shfl_xor(den, 16);
    den += __shfl_xor(den, 32);
#pragma unroll
    for (int k = 0; k < 8; k++) {
        ac[k] += __shfl_xor(ac[k], 16);
        ac[k] += __shfl_xor(ac[k], 32);
    }
    const float wself = __expf(lrelu(as1[n * HEADS + fh] + adn));
    den += wself;

    // out1 row (bf16-rounded, matching previous out1 store semantics)
    unsigned pk01, pk23, pk45, pk67;
    {
        unsigned offs = ((unsigned)n << 8) + (unsigned)(ll << 4);
        uint4 sp = *(const uint4*)((const char*)h1b + offs);
        float sv[8] = {bflo(sp.x), bfhi(sp.x), bflo(sp.y), bfhi(sp.y),
                       bflo(sp.z), bfhi(sp.z), bflo(sp.w), bfhi(sp.w)};
        float4 bv0 = *(const float4*)(b1 + ll * 8);
        float4 bv1 = *(const float4*)(b1 + ll * 8 + 4);
        float bb[8] = {bv0.x, bv0.y, bv0.z, bv0.w, bv1.x, bv1.y, bv1.z, bv1.w};
        float o[8];
#pragma unroll
        for (int k = 0; k < 8; k++)
            o[k] = fmaxf((ac[k] + wself * sv[k]) / den + bb[k], 0.f);
        pk01 = (unsigned)f2bf(o[0]) | ((unsigned)f2bf(o[1]) << 16);
        pk23 = (unsigned)f2bf(o[2]) | ((unsigned)f2bf(o[3]) << 16);
        pk45 = (unsigned)f2bf(o[4]) | ((unsigned)f2bf(o[5]) << 16);
        pk67 = (unsigned)f2bf(o[6]) | ((unsigned)f2bf(o[7]) << 16);
    }
    // GEMM2 via MFMA: A row 0 = out1 row; rows 1..15 zero
    f32x4 a2[3];
#pragma unroll
    for (int ct = 0; ct < 3; ct++) a2[ct] = (f32x4){0.f, 0.f, 0.f, 0.f};
#pragma unroll
    for (int kt = 0; kt < 4; kt++) {
        int sl = kt * 4 + q;       // source lane holding channels kt*32+q*8..+7
        BF8 af;
        af.u.x = (unsigned)__shfl((int)pk01, sl);
        af.u.y = (unsigned)__shfl((int)pk23, sl);
        af.u.z = (unsigned)__shfl((int)pk45, sl);
        af.u.w = (unsigned)__shfl((int)pk67, sl);
        if (ll != 0) af.u = make_uint4(0, 0, 0, 0);
#pragma unroll
        for (int ct = 0; ct < 3; ct++) {
            bf16x8 b = *(const bf16x8*)(&Wt2[ct * 16 + ll][kt * 32 + q * 8]);
            a2[ct] = __builtin_amdgcn_mfma_f32_16x16x32_bf16(af.v, b, a2[ct], 0, 0, 0);
        }
    }
    // C row 0 in lanes q==0 reg 0 (other lanes' reg0 = rows 4q = zero)
    float s = 0.f, d = 0.f;
#pragma unroll
    for (int ct = 0; ct < 3; ct++) {
        int c = ct * 16 + ll;
        float hv = a2[ct][0];
        if (c < CLS) {
            if (q == 0) h2b[(size_t)n * 64 + c] = f2bf(hv);
            s = fmaf(hv, AS2[c], s);
            d = fmaf(hv, AD2[c], d);
        }
    }
#pragma unroll
    for (int dd = 1; dd < 64; dd <<= 1) {
        s += __shfl_xor(s, dd);
        d += __shfl_xor(d, dd);
    }
    if (lane == 0) { as2[n] = s; ad2[n] = d; }
}

// ---- layer-2 aggregation: one wave per dst node ----
__global__ __launch_bounds__(256) void k_agg2(const unsigned short* __restrict__ h2b,
                                              const float* __restrict__ as2,
                                              const float* __restrict__ ad2,
                                              const int* __restrict__ rowptr,
                                              const int* __restrict__ degarr,
                                              const int* __restrict__ col,
                                              const float* __restrict__ b2,
                                              float* __restrict__ out) {
    int wid = (blockIdx.x * 256 + threadIdx.x) >> 6;
    if (wid >= NODES) return;
    const int lane = threadIdx.x & 63;
    const int q8 = lane >> 3, l8 = lane & 7;
    const int n = wid;
    const float adn = ad2[n];
    const int rs = rowptr[n];
    const int re = rs + degarr[n];

    float den = 0.f;
    float ac[8];
#pragma unroll
    for (int k = 0; k < 8; k++) ac[k] = 0.f;

    int base = rs;
    for (; base + 16 <= re; base += 16) {
        int2a cc = *(const int2a*)(col + base + q8 * 2);
        float w0 = __expf(lrelu(as2[cc.x] + adn));
        float w1 = __expf(lrelu(as2[cc.y] + adn));
        den += w0 + w1;
        if (l8 < 5) {
            unsigned o0 = ((unsigned)cc.x << 7) + (unsigned)(l8 << 4);
            unsigned o1 = ((unsigned)cc.y << 7) + (unsigned)(l8 << 4);
            uint4 p0 = *(const uint4*)((const char*)h2b + o0);
            uint4 p1 = *(const uint4*)((const char*)h2b + o1);
            ac[0] = fmaf(w0, bflo(p0.x), ac[0]); ac[1] = fmaf(w0, bfhi(p0.x), ac[1]);
            ac[2] = fmaf(w0, bflo(p0.y), ac[2]); ac[3] = fmaf(w0, bfhi(p0.y), ac[3]);
            ac[4] = fmaf(w0, bflo(p0.z), ac[4]); ac[5] = fmaf(w0, bfhi(p0.z), ac[5]);
            ac[6] = fmaf(w0, bflo(p0.w), ac[6]); ac[7] = fmaf(w0, bfhi(p0.w), ac[7]);
            ac[0] = fmaf(w1, bflo(p1.x), ac[0]); ac[1] = fmaf(w1, bfhi(p1.x), ac[1]);
            ac[2] = fmaf(w1, bflo(p1.y), ac[2]); ac[3] = fmaf(w1, bfhi(p1.y), ac[3]);
            ac[4] = fmaf(w1, bflo(p1.z), ac[4]); ac[5] = fmaf(w1, bfhi(p1.z), ac[5]);
            ac[6] = fmaf(w1, bflo(p1.w), ac[6]); ac[7] = fmaf(w1, bfhi(p1.w), ac[7]);
        }
    }
    for (; base < re; base += 8) {
        int i = base + q8;
        int c = (i < re) ? col[i] : n;
        float w = __expf(lrelu(as2[c] + adn));
        if (i >= re) w = 0.f;
        den += w;
        if (l8 < 5) {
            unsigned off = ((unsigned)c << 7) + (unsigned)(l8 << 4);
            uint4 pk = *(const uint4*)((const char*)h2b + off);
            ac[0] = fmaf(w, bflo(pk.x), ac[0]); ac[1] = fmaf(w, bfhi(pk.x), ac[1]);
            ac[2] = fmaf(w, bflo(pk.y), ac[2]); ac[3] = fmaf(w, bfhi(pk.y), ac[3]);
            ac[4] = fmaf(w, bflo(pk.z), ac[4]); ac[5] = fmaf(w, bfhi(pk.z), ac[5]);
            ac[6] = fmaf(w, bflo(pk.w), ac[6]); ac[7] = fmaf(w, bfhi(pk.w), ac[7]);
        }
    }
    den += __shfl_xor(den, 8);
    den += __shfl_xor(den, 16);
    den += __shfl_xor(den, 32);
#pragma unroll
    for (int k = 0; k < 8; k++) {
        ac[k] += __shfl_xor(ac[k], 8);
        ac[k] += __shfl_xor(ac[k], 16);
        ac[k] += __shfl_xor(ac[k], 32);
    }
    const float wself = __expf(lrelu(as2[n] + adn));
    den += wself;
    if (q8 == 0 && l8 < 5) {
        unsigned offs = ((unsigned)n << 7) + (unsigned)(l8 << 4);
        uint4 sp = *(const uint4*)((const char*)h2b + offs);
        float sv[8] = {bflo(sp.x), bfhi(sp.x), bflo(sp.y), bfhi(sp.y),
                       bflo(sp.z), bfhi(sp.z), bflo(sp.w), bfhi(sp.w)};
        float4 bv0 = *(const float4*)(b2 + l8 * 8);
        float4 bv1 = *(const float4*)(b2 + l8 * 8 + 4);
        float bb[8] = {bv0.x, bv0.y, bv0.z, bv0.w, bv1.x, bv1.y, bv1.z, bv1.w};
        float o[8];
#pragma unroll
        for (int k = 0; k < 8; k++)
            o[k] = (ac[k] + wself * sv[k]) / den + bb[k];
        *(float4*)(out + (size_t)n * CLS + l8 * 8) =
            make_float4(o[0], o[1], o[2], o[3]);
        *(float4*)(out + (size_t)n * CLS + l8 * 8 + 4) =
            make_float4(o[4], o[5], o[6], o[7]);
    }
}

extern "C" void kernel_launch(void* const* d_in, const int* in_sizes, int n_in,
                              void* d_out, int out_size, void* d_ws, size_t ws_size,
                              hipStream_t stream) {
    const float* x     = (const float*)d_in[0];
    const int*   ei    = (const int*)d_in[1];
    const float* W1    = (const float*)d_in[2];
    const float* aS1   = (const float*)d_in[3];
    const float* aD1   = (const float*)d_in[4];
    const float* b1    = (const float*)d_in[5];
    const float* W2    = (const float*)d_in[6];
    const float* aS2   = (const float*)d_in[7];
    const float* aD2   = (const float*)d_in[8];
    const float* b2    = (const float*)d_in[9];
    float* out = (float*)d_out;
    const int E = in_sizes[1] / 2;
    const int* src = ei;
    const int* dst = ei + E;

    char* ws = (char*)d_ws;
    size_t off = 0;
    auto alloc = [&](size_t bytes) -> char* {
        char* p = ws + off;
        off += (bytes + 255) & ~(size_t)255;
        return p;
    };
    unsigned short* h1b  = (unsigned short*)alloc((size_t)NODES * C1 * 2);
    unsigned short* h2b  = (unsigned short*)alloc((size_t)NODES * 64 * 2);
    float* as1    = (float*)alloc((size_t)NODES * HEADS * 4);
    float* ad1    = (float*)alloc((size_t)NODES * HEADS * 4);
    float* as2    = (float*)alloc((size_t)NODES * 4);
    float* ad2    = (float*)alloc((size_t)NODES * 4);
    int* rowptr   = (int*)alloc((size_t)NODES * 4);
    int* degarr   = (int*)alloc((size_t)NODES * 4);
    int* col      = (int*)alloc((size_t)NBUCK * BCAP * 4);
    int* tmp      = (int*)alloc((size_t)NBUCK * BCAP * 4);
    unsigned short* w1t = (unsigned short*)alloc((size_t)FIN * C1 * 2);
    unsigned short* w2t = (unsigned short*)alloc((size_t)CLS * 128 * 2);
    int* bwp      = (int*)alloc((size_t)NBUCK * 4);

    const int GB1 = (NODES + 63) / 64;           // 782 gemm1 blocks
    const int GBA = (E + EPB - 1) / EPB;         // bucketA blocks

    k_prep<<<1, 256, 0, stream>>>(W1, W2, w1t, w2t, bwp);
    k_front<<<GB1 + GBA, 256, 0, stream>>>(x, w1t, aS1, aD1, h1b, as1, ad1,
                                           src, dst, E, bwp, tmp, GB1);
    k_bucketB<<<NBUCK, 256, 0, stream>>>(bwp, tmp, col, rowptr, degarr);
    k_agg1<<<(NODES * 64) / 256, 256, 0, stream>>>(h1b, as1, ad1, rowptr, degarr,
                                                   col, b1, w2t, aS2, aD2,
                                                   h2b, as2, ad2);
    k_agg2<<<(NODES * 64) / 256, 256, 0, stream>>>(h2b, as2, ad2, rowptr, degarr,
                                                   col, b2, out);
}

// Round 15
// 201.311 us; speedup vs baseline: 1.0922x; 1.0922x over previous
//
#include <hip/hip_runtime.h>
#include <cstdint>

#define NODES 50000
#define FIN   128
#define C1    128   // HEADS*HID
#define HEADS 4
#define HID   32
#define CLS   40
#define SLOPE 0.2f

#define NBUCK ((NODES + 255) >> 8)   // 196
#define EPB 2048                     // edges per bucketA block
#define BCAP 8192                    // fixed bucket capacity (max actual ~4.3k)

__device__ __forceinline__ float lrelu(float v) { return v > 0.f ? v : SLOPE * v; }

__device__ __forceinline__ unsigned short f2bf(float f) {
    union { float f; unsigned u; } v; v.f = f;
    unsigned u = v.u;
    return (unsigned short)((u + 0x7FFFu + ((u >> 16) & 1u)) >> 16);
}
__device__ __forceinline__ float bf2f(unsigned short b) {
    union { unsigned u; float f; } v; v.u = ((unsigned)b) << 16;
    return v.f;
}
__device__ __forceinline__ float bflo(unsigned u) {
    union { unsigned x; float f; } v; v.x = u << 16; return v.f;
}
__device__ __forceinline__ float bfhi(unsigned u) {
    union { unsigned x; float f; } v; v.x = u & 0xffff0000u; return v.f;
}

typedef __attribute__((ext_vector_type(8))) short bf16x8;
typedef __attribute__((ext_vector_type(4))) float f32x4;
typedef __attribute__((ext_vector_type(4), aligned(4))) int int4a;
typedef __attribute__((ext_vector_type(2), aligned(4))) int int2a;

// ---- prep: W1->bf16 transposed (LDS-coalesced), W2->bf16 transposed, bwp init ----
__global__ __launch_bounds__(256) void k_prep(const float* __restrict__ W1,
                                              const float* __restrict__ W2,
                                              unsigned short* __restrict__ w1t,
                                              unsigned short* __restrict__ w2t,
                                              int* __restrict__ bwp) {
    __shared__ unsigned short Tb[128][136];
    const int t = threadIdx.x;
#pragma unroll
    for (int i = 0; i < 64; i++) {
        int p = i * 256 + t;
        int k = p >> 7, n = p & 127;
        Tb[n][k] = f2bf(W1[(size_t)k * C1 + n]);
    }
    __syncthreads();
#pragma unroll
    for (int i = 0; i < 8; i++) {
        int p = i * 256 + t;
        int n = p >> 4, k8 = (p & 15) * 8;
        *(uint4*)(w1t + n * 128 + k8) = *(uint4*)(&Tb[n][k8]);
    }
    for (int p = t; p < CLS * 128; p += 256) {
        int n = p >> 7, k = p & 127;
        w2t[n * 128 + k] = f2bf(W2[(size_t)k * CLS + n]);
    }
    if (t < NBUCK) bwp[t] = t * BCAP;
}

// ---- front: blocks [0,GB1) = GEMM1 (MFMA bf16 + fused att1);
//             blocks [GB1,..) = bucketA (independent inputs/outputs) ----
__global__ __launch_bounds__(256) void k_front(const float* __restrict__ X,
                                               const unsigned short* __restrict__ w1t,
                                               const float* __restrict__ AS,
                                               const float* __restrict__ AD,
                                               unsigned short* __restrict__ h1b,
                                               float* __restrict__ as1,
                                               float* __restrict__ ad1,
                                               const int* __restrict__ src,
                                               const int* __restrict__ dst, int E,
                                               int* __restrict__ bwp,
                                               int* __restrict__ tmp, int GB1) {
    __shared__ unsigned short Asm[64][136];
    __shared__ unsigned short Wt[128][136];
    __shared__ int cnt[NBUCK];
    __shared__ int bbs[NBUCK];
    const int t = threadIdx.x;

    if (blockIdx.x >= GB1) {
        // ---------------- bucketA body ----------------
        for (int i = t; i < NBUCK; i += 256) cnt[i] = 0;
        __syncthreads();
        const int e0 = (blockIdx.x - GB1) * EPB;
        int v[8], rb[8];
#pragma unroll
        for (int k = 0; k < 8; k++) {
            int e = e0 + k * 256 + t;
            rb[k] = -1;
            if (e < E) {
                int d = dst[e], s = src[e];
                int b = d >> 8;
                int r = atomicAdd(&cnt[b], 1);
                v[k] = (s << 8) | (d & 255);
                rb[k] = (r << 8) | b;
            }
        }
        __syncthreads();
        for (int i = t; i < NBUCK; i += 256) {
            int c = cnt[i];
            bbs[i] = c ? atomicAdd(&bwp[i], c) : 0;
        }
        __syncthreads();
#pragma unroll
        for (int k = 0; k < 8; k++) {
            if (rb[k] >= 0) {
                int b = rb[k] & 255;
                int r = rb[k] >> 8;
                tmp[bbs[b] + r] = v[k];
            }
        }
        return;
    }

    // ---------------- GEMM1 body ----------------
    const int row0 = blockIdx.x * 64;
#pragma unroll
    for (int i = 0; i < 8; i++) {
        int p = i * 256 + t;
        int n = p >> 4, k8 = (p & 15) * 8;
        *(uint4*)(&Wt[n][k8]) = *(const uint4*)(w1t + n * 128 + k8);
    }
    {
        int r = t >> 2, c0 = (t & 3) * 32;
        int gr = row0 + r;
        unsigned short tb[32];
        if (gr < NODES) {
#pragma unroll
            for (int i = 0; i < 8; i++) {
                float4 v = *(const float4*)(X + (size_t)gr * FIN + c0 + i * 4);
                tb[i * 4 + 0] = f2bf(v.x); tb[i * 4 + 1] = f2bf(v.y);
                tb[i * 4 + 2] = f2bf(v.z); tb[i * 4 + 3] = f2bf(v.w);
            }
        } else {
#pragma unroll
            for (int i = 0; i < 32; i++) tb[i] = 0;
        }
#pragma unroll
        for (int i = 0; i < 4; i++) {
            uint4 pk;
            pk.x = (unsigned)tb[i*8+0] | ((unsigned)tb[i*8+1] << 16);
            pk.y = (unsigned)tb[i*8+2] | ((unsigned)tb[i*8+3] << 16);
            pk.z = (unsigned)tb[i*8+4] | ((unsigned)tb[i*8+5] << 16);
            pk.w = (unsigned)tb[i*8+6] | ((unsigned)tb[i*8+7] << 16);
            *(uint4*)(&Asm[r][c0 + i * 8]) = pk;
        }
    }
    __syncthreads();

    const int w = t >> 6, l = t & 63;
    const int lm = l & 15, quad = l >> 4;
    f32x4 acc[8];
#pragma unroll
    for (int ct = 0; ct < 8; ct++) acc[ct] = (f32x4){0.f, 0.f, 0.f, 0.f};
#pragma unroll
    for (int kt = 0; kt < 4; kt++) {
        bf16x8 a = *(const bf16x8*)(&Asm[w * 16 + lm][kt * 32 + quad * 8]);
#pragma unroll
        for (int ct = 0; ct < 8; ct++) {
            bf16x8 b = *(const bf16x8*)(&Wt[ct * 16 + lm][kt * 32 + quad * 8]);
            acc[ct] = __builtin_amdgcn_mfma_f32_16x16x32_bf16(a, b, acc[ct], 0, 0, 0);
        }
    }
    __syncthreads();
#pragma unroll
    for (int ct = 0; ct < 8; ct++)
#pragma unroll
        for (int r = 0; r < 4; r++)
            Asm[w * 16 + quad * 4 + r][ct * 16 + lm] = f2bf(acc[ct][r]);
    __syncthreads();
    {
        int r = t >> 2, c0 = (t & 3) * 32;
        int gr = row0 + r;
        if (gr < NODES) {
#pragma unroll
            for (int i = 0; i < 4; i++)
                *(uint4*)(h1b + (size_t)gr * C1 + c0 + i * 8) =
                    *(uint4*)(&Asm[r][c0 + i * 8]);
        }
    }
    {
        int r = t >> 2, h = t & 3;
        int gr = row0 + r;
        if (gr < NODES) {
            float s = 0.f, d = 0.f;
#pragma unroll
            for (int j = 0; j < 32; j++) {
                float v = bf2f(Asm[r][h * 32 + j]);
                s = fmaf(v, AS[h * HID + j], s);
                d = fmaf(v, AD[h * HID + j], d);
            }
            as1[gr * HEADS + h] = s;
            ad1[gr * HEADS + h] = d;
        }
    }
}

// ---- pass B: per-bucket degree+scan -> rowptr/deg, scatter col ----
__global__ __launch_bounds__(256) void k_bucketB(const int* __restrict__ bwp,
                                                 const int* __restrict__ tmp,
                                                 int* __restrict__ col,
                                                 int* __restrict__ rowptr,
                                                 int* __restrict__ degarr) {
    __shared__ int degs[256];
    __shared__ int wp[256];
    __shared__ int wsum[4];
    const int b = blockIdx.x, t = threadIdx.x;
    const int n0 = b << 8;
    const int beg = b * BCAP;
    const int end = bwp[b];
    degs[t] = 0;
    __syncthreads();
    for (int e = beg + t; e < end; e += 256)
        atomicAdd(&degs[tmp[e] & 255], 1);
    __syncthreads();
    const int d = degs[t];
    int incl = d;
    const int lane = t & 63, w = t >> 6;
#pragma unroll
    for (int s = 1; s < 64; s <<= 1) {
        int u = __shfl_up(incl, s);
        if (lane >= s) incl += u;
    }
    if (lane == 63) wsum[w] = incl;
    __syncthreads();
    if (t == 0) {
        int r = 0;
#pragma unroll
        for (int i = 0; i < 4; i++) { int x = wsum[i]; wsum[i] = r; r += x; }
    }
    __syncthreads();
    const int excl = incl - d + wsum[w] + beg;
    const int nidx = n0 + t;
    if (nidx < NODES) { rowptr[nidx] = excl; degarr[nidx] = d; }
    wp[t] = excl;
    __syncthreads();
    for (int e = beg + t; e < end; e += 256) {
        int v = tmp[e];
        int p = atomicAdd(&wp[v & 255], 1);
        col[p] = v >> 8;
    }
}

// ---- layer-1 aggregation: one wave per dst node; out1 written bf16 ----
__global__ __launch_bounds__(256) void k_agg1(const unsigned short* __restrict__ h1b,
                                              const float* __restrict__ as1,
                                              const float* __restrict__ ad1,
                                              const int* __restrict__ rowptr,
                                              const int* __restrict__ degarr,
                                              const int* __restrict__ col,
                                              const float* __restrict__ b1,
                                              unsigned short* __restrict__ out1) {
    int wid = (blockIdx.x * 256 + threadIdx.x) >> 6;
    if (wid >= NODES) return;
    const int lane = threadIdx.x & 63;
    const int q  = lane >> 4;       // edge slot
    const int ll = lane & 15;       // channel group
    const int fh = ll >> 2;         // head
    const int n = wid;
    const float adn = ad1[n * HEADS + fh];
    const int rs = rowptr[n];
    const int re = rs + degarr[n];

    float den = 0.f;
    float ac[8];
#pragma unroll
    for (int k = 0; k < 8; k++) ac[k] = 0.f;

    int base = rs;
    for (; base + 16 <= re; base += 16) {
        int4a cc = *(const int4a*)(col + base + q * 4);
        float w0 = __expf(lrelu(as1[cc.x * HEADS + fh] + adn));
        float w1 = __expf(lrelu(as1[cc.y * HEADS + fh] + adn));
        float w2 = __expf(lrelu(as1[cc.z * HEADS + fh] + adn));
        float w3 = __expf(lrelu(as1[cc.w * HEADS + fh] + adn));
        den += (w0 + w1) + (w2 + w3);
        uint4 p0 = *(const uint4*)((const char*)h1b + (((unsigned)cc.x << 8) + (unsigned)(ll << 4)));
        uint4 p1 = *(const uint4*)((const char*)h1b + (((unsigned)cc.y << 8) + (unsigned)(ll << 4)));
        uint4 p2 = *(const uint4*)((const char*)h1b + (((unsigned)cc.z << 8) + (unsigned)(ll << 4)));
        uint4 p3 = *(const uint4*)((const char*)h1b + (((unsigned)cc.w << 8) + (unsigned)(ll << 4)));
        ac[0] = fmaf(w0, bflo(p0.x), ac[0]); ac[1] = fmaf(w0, bfhi(p0.x), ac[1]);
        ac[2] = fmaf(w0, bflo(p0.y), ac[2]); ac[3] = fmaf(w0, bfhi(p0.y), ac[3]);
        ac[4] = fmaf(w0, bflo(p0.z), ac[4]); ac[5] = fmaf(w0, bfhi(p0.z), ac[5]);
        ac[6] = fmaf(w0, bflo(p0.w), ac[6]); ac[7] = fmaf(w0, bfhi(p0.w), ac[7]);
        ac[0] = fmaf(w1, bflo(p1.x), ac[0]); ac[1] = fmaf(w1, bfhi(p1.x), ac[1]);
        ac[2] = fmaf(w1, bflo(p1.y), ac[2]); ac[3] = fmaf(w1, bfhi(p1.y), ac[3]);
        ac[4] = fmaf(w1, bflo(p1.z), ac[4]); ac[5] = fmaf(w1, bfhi(p1.z), ac[5]);
        ac[6] = fmaf(w1, bflo(p1.w), ac[6]); ac[7] = fmaf(w1, bfhi(p1.w), ac[7]);
        ac[0] = fmaf(w2, bflo(p2.x), ac[0]); ac[1] = fmaf(w2, bfhi(p2.x), ac[1]);
        ac[2] = fmaf(w2, bflo(p2.y), ac[2]); ac[3] = fmaf(w2, bfhi(p2.y), ac[3]);
        ac[4] = fmaf(w2, bflo(p2.z), ac[4]); ac[5] = fmaf(w2, bfhi(p2.z), ac[5]);
        ac[6] = fmaf(w2, bflo(p2.w), ac[6]); ac[7] = fmaf(w2, bfhi(p2.w), ac[7]);
        ac[0] = fmaf(w3, bflo(p3.x), ac[0]); ac[1] = fmaf(w3, bfhi(p3.x), ac[1]);
        ac[2] = fmaf(w3, bflo(p3.y), ac[2]); ac[3] = fmaf(w3, bfhi(p3.y), ac[3]);
        ac[4] = fmaf(w3, bflo(p3.z), ac[4]); ac[5] = fmaf(w3, bfhi(p3.z), ac[5]);
        ac[6] = fmaf(w3, bflo(p3.w), ac[6]); ac[7] = fmaf(w3, bfhi(p3.w), ac[7]);
    }
    for (; base < re; base += 4) {
        int i = base + q;
        int c = (i < re) ? col[i] : n;
        float w = __expf(lrelu(as1[c * HEADS + fh] + adn));
        if (i >= re) w = 0.f;
        den += w;
        unsigned off = ((unsigned)c << 8) + (unsigned)(ll << 4);
        uint4 pk = *(const uint4*)((const char*)h1b + off);
        ac[0] = fmaf(w, bflo(pk.x), ac[0]); ac[1] = fmaf(w, bfhi(pk.x), ac[1]);
        ac[2] = fmaf(w, bflo(pk.y), ac[2]); ac[3] = fmaf(w, bfhi(pk.y), ac[3]);
        ac[4] = fmaf(w, bflo(pk.z), ac[4]); ac[5] = fmaf(w, bfhi(pk.z), ac[5]);
        ac[6] = fmaf(w, bflo(pk.w), ac[6]); ac[7] = fmaf(w, bfhi(pk.w), ac[7]);
    }
    den += __shfl_xor(den, 16);
    den += __shfl_xor(den, 32);
#pragma unroll
    for (int k = 0; k < 8; k++) {
        ac[k] += __shfl_xor(ac[k], 16);
        ac[k] += __shfl_xor(ac[k], 32);
    }
    const float wself = __expf(lrelu(as1[n * HEADS + fh] + adn));
    den += wself;
    if (q == 0) {
        unsigned offs = ((unsigned)n << 8) + (unsigned)(ll << 4);
        uint4 sp = *(const uint4*)((const char*)h1b + offs);
        float sv[8] = {bflo(sp.x), bfhi(sp.x), bflo(sp.y), bfhi(sp.y),
                       bflo(sp.z), bfhi(sp.z), bflo(sp.w), bfhi(sp.w)};
        float4 bv0 = *(const float4*)(b1 + ll * 8);
        float4 bv1 = *(const float4*)(b1 + ll * 8 + 4);
        float bb[8] = {bv0.x, bv0.y, bv0.z, bv0.w, bv1.x, bv1.y, bv1.z, bv1.w};
        unsigned short ob[8];
#pragma unroll
        for (int k = 0; k < 8; k++)
            ob[k] = f2bf(fmaxf((ac[k] + wself * sv[k]) / den + bb[k], 0.f));
        uint4 pk;
        pk.x = (unsigned)ob[0] | ((unsigned)ob[1] << 16);
        pk.y = (unsigned)ob[2] | ((unsigned)ob[3] << 16);
        pk.z = (unsigned)ob[4] | ((unsigned)ob[5] << 16);
        pk.w = (unsigned)ob[6] | ((unsigned)ob[7] << 16);
        *(uint4*)(out1 + (size_t)n * C1 + ll * 8) = pk;
    }
}

// ---- GEMM2 (MFMA bf16, fused att2): h2b[N,64](bf16) = out1 @ W2 ; as2/ad2 ----
__global__ __launch_bounds__(256) void k_gemm2(const unsigned short* __restrict__ out1b,
                                               const unsigned short* __restrict__ w2t,
                                               const float* __restrict__ AS,
                                               const float* __restrict__ AD,
                                               unsigned short* __restrict__ h2b,
                                               float* __restrict__ as2,
                                               float* __restrict__ ad2) {
    __shared__ unsigned short Asm[64][136];
    __shared__ unsigned short Wt2[48][136];
    __shared__ float Cc[64][52];
    const int t = threadIdx.x;
    const int row0 = blockIdx.x * 64;

    for (int p = t; p < 8 * 136; p += 256) Wt2[40 + p / 136][p % 136] = 0;
    for (int p = t; p < 640; p += 256) {
        int n = p >> 4, k8 = (p & 15) * 8;
        *(uint4*)(&Wt2[n][k8]) = *(const uint4*)(w2t + n * 128 + k8);
    }
    {
        int r = t >> 2, c0 = (t & 3) * 32;
        int gr = row0 + r;
        if (gr < NODES) {
#pragma unroll
            for (int i = 0; i < 4; i++)
                *(uint4*)(&Asm[r][c0 + i * 8]) =
                    *(const uint4*)(out1b + (size_t)gr * C1 + c0 + i * 8);
        } else {
            uint4 z = make_uint4(0, 0, 0, 0);
#pragma unroll
            for (int i = 0; i < 4; i++) *(uint4*)(&Asm[r][c0 + i * 8]) = z;
        }
    }
    __syncthreads();

    const int w = t >> 6, l = t & 63;
    const int lm = l & 15, quad = l >> 4;
    f32x4 acc[3];
#pragma unroll
    for (int ct = 0; ct < 3; ct++) acc[ct] = (f32x4){0.f, 0.f, 0.f, 0.f};
#pragma unroll
    for (int kt = 0; kt < 4; kt++) {
        bf16x8 a = *(const bf16x8*)(&Asm[w * 16 + lm][kt * 32 + quad * 8]);
#pragma unroll
        for (int ct = 0; ct < 3; ct++) {
            bf16x8 b = *(const bf16x8*)(&Wt2[ct * 16 + lm][kt * 32 + quad * 8]);
            acc[ct] = __builtin_amdgcn_mfma_f32_16x16x32_bf16(a, b, acc[ct], 0, 0, 0);
        }
    }
    __syncthreads();
#pragma unroll
    for (int ct = 0; ct < 3; ct++)
#pragma unroll
        for (int r = 0; r < 4; r++)
            Cc[w * 16 + quad * 4 + r][ct * 16 + lm] = acc[ct][r];
    __syncthreads();
    {
        int r = t >> 2, c0 = (t & 3) * 10;
        int gr = row0 + r;
        if (gr < NODES) {
#pragma unroll
            for (int i = 0; i < 5; i++) {
                int c = c0 + i * 2;
                unsigned pk = (unsigned)f2bf(Cc[r][c]) |
                              ((unsigned)f2bf(Cc[r][c + 1]) << 16);
                *(unsigned*)(h2b + (size_t)gr * 64 + c) = pk;
            }
            float s = 0.f, d = 0.f;
#pragma unroll
            for (int j = 0; j < 10; j++) {
                float v = Cc[r][c0 + j];
                s = fmaf(v, AS[c0 + j], s);
                d = fmaf(v, AD[c0 + j], d);
            }
            s += __shfl_xor(s, 1); s += __shfl_xor(s, 2);
            d += __shfl_xor(d, 1); d += __shfl_xor(d, 2);
            if ((t & 3) == 0) { as2[gr] = s; ad2[gr] = d; }
        }
    }
}

// ---- layer-2 aggregation: one wave per dst node ----
__global__ __launch_bounds__(256) void k_agg2(const unsigned short* __restrict__ h2b,
                                              const float* __restrict__ as2,
                                              const float* __restrict__ ad2,
                                              const int* __restrict__ rowptr,
                                              const int* __restrict__ degarr,
                                              const int* __restrict__ col,
                                              const float* __restrict__ b2,
                                              float* __restrict__ out) {
    int wid = (blockIdx.x * 256 + threadIdx.x) >> 6;
    if (wid >= NODES) return;
    const int lane = threadIdx.x & 63;
    const int q8 = lane >> 3, l8 = lane & 7;
    const int n = wid;
    const float adn = ad2[n];
    const int rs = rowptr[n];
    const int re = rs + degarr[n];

    float den = 0.f;
    float ac[8];
#pragma unroll
    for (int k = 0; k < 8; k++) ac[k] = 0.f;

    int base = rs;
    for (; base + 16 <= re; base += 16) {
        int2a cc = *(const int2a*)(col + base + q8 * 2);
        float w0 = __expf(lrelu(as2[cc.x] + adn));
        float w1 = __expf(lrelu(as2[cc.y] + adn));
        den += w0 + w1;
        if (l8 < 5) {
            unsigned o0 = ((unsigned)cc.x << 7) + (unsigned)(l8 << 4);
            unsigned o1 = ((unsigned)cc.y << 7) + (unsigned)(l8 << 4);
            uint4 p0 = *(const uint4*)((const char*)h2b + o0);
            uint4 p1 = *(const uint4*)((const char*)h2b + o1);
            ac[0] = fmaf(w0, bflo(p0.x), ac[0]); ac[1] = fmaf(w0, bfhi(p0.x), ac[1]);
            ac[2] = fmaf(w0, bflo(p0.y), ac[2]); ac[3] = fmaf(w0, bfhi(p0.y), ac[3]);
            ac[4] = fmaf(w0, bflo(p0.z), ac[4]); ac[5] = fmaf(w0, bfhi(p0.z), ac[5]);
            ac[6] = fmaf(w0, bflo(p0.w), ac[6]); ac[7] = fmaf(w0, bfhi(p0.w), ac[7]);
            ac[0] = fmaf(w1, bflo(p1.x), ac[0]); ac[1] = fmaf(w1, bfhi(p1.x), ac[1]);
            ac[2] = fmaf(w1, bflo(p1.y), ac[2]); ac[3] = fmaf(w1, bfhi(p1.y), ac[3]);
            ac[4] = fmaf(w1, bflo(p1.z), ac[4]); ac[5] = fmaf(w1, bfhi(p1.z), ac[5]);
            ac[6] = fmaf(w1, bflo(p1.w), ac[6]); ac[7] = fmaf(w1, bfhi(p1.w), ac[7]);
        }
    }
    for (; base < re; base += 8) {
        int i = base + q8;
        int c = (i < re) ? col[i] : n;
        float w = __expf(lrelu(as2[c] + adn));
        if (i >= re) w = 0.f;
        den += w;
        if (l8 < 5) {
            unsigned off = ((unsigned)c << 7) + (unsigned)(l8 << 4);
            uint4 pk = *(const uint4*)((const char*)h2b + off);
            ac[0] = fmaf(w, bflo(pk.x), ac[0]); ac[1] = fmaf(w, bfhi(pk.x), ac[1]);
            ac[2] = fmaf(w, bflo(pk.y), ac[2]); ac[3] = fmaf(w, bfhi(pk.y), ac[3]);
            ac[4] = fmaf(w, bflo(pk.z), ac[4]); ac[5] = fmaf(w, bfhi(pk.z), ac[5]);
            ac[6] = fmaf(w, bflo(pk.w), ac[6]); ac[7] = fmaf(w, bfhi(pk.w), ac[7]);
        }
    }
    den += __shfl_xor(den, 8);
    den += __shfl_xor(den, 16);
    den += __shfl_xor(den, 32);
#pragma unroll
    for (int k = 0; k < 8; k++) {
        ac[k] += __shfl_xor(ac[k], 8);
        ac[k] += __shfl_xor(ac[k], 16);
        ac[k] += __shfl_xor(ac[k], 32);
    }
    const float wself = __expf(lrelu(as2[n] + adn));
    den += wself;
    if (q8 == 0 && l8 < 5) {
        unsigned offs = ((unsigned)n << 7) + (unsigned)(l8 << 4);
        uint4 sp = *(const uint4*)((const char*)h2b + offs);
        float sv[8] = {bflo(sp.x), bfhi(sp.x), bflo(sp.y), bfhi(sp.y),
                       bflo(sp.z), bfhi(sp.z), bflo(sp.w), bfhi(sp.w)};
        float4 bv0 = *(const float4*)(b2 + l8 * 8);
        float4 bv1 = *(const float4*)(b2 + l8 * 8 + 4);
        float bb[8] = {bv0.x, bv0.y, bv0.z, bv0.w, bv1.x, bv1.y, bv1.z, bv1.w};
        float o[8];
#pragma unroll
        for (int k = 0; k < 8; k++)
            o[k] = (ac[k] + wself * sv[k]) / den + bb[k];
        *(float4*)(out + (size_t)n * CLS + l8 * 8) =
            make_float4(o[0], o[1], o[2], o[3]);
        *(float4*)(out + (size_t)n * CLS + l8 * 8 + 4) =
            make_float4(o[4], o[5], o[6], o[7]);
    }
}

extern "C" void kernel_launch(void* const* d_in, const int* in_sizes, int n_in,
                              void* d_out, int out_size, void* d_ws, size_t ws_size,
                              hipStream_t stream) {
    const float* x     = (const float*)d_in[0];
    const int*   ei    = (const int*)d_in[1];
    const float* W1    = (const float*)d_in[2];
    const float* aS1   = (const float*)d_in[3];
    const float* aD1   = (const float*)d_in[4];
    const float* b1    = (const float*)d_in[5];
    const float* W2    = (const float*)d_in[6];
    const float* aS2   = (const float*)d_in[7];
    const float* aD2   = (const float*)d_in[8];
    const float* b2    = (const float*)d_in[9];
    float* out = (float*)d_out;
    const int E = in_sizes[1] / 2;
    const int* src = ei;
    const int* dst = ei + E;

    char* ws = (char*)d_ws;
    size_t off = 0;
    auto alloc = [&](size_t bytes) -> char* {
        char* p = ws + off;
        off += (bytes + 255) & ~(size_t)255;
        return p;
    };
    unsigned short* h1b  = (unsigned short*)alloc((size_t)NODES * C1 * 2);
    unsigned short* out1 = (unsigned short*)alloc((size_t)NODES * C1 * 2);
    unsigned short* h2b  = (unsigned short*)alloc((size_t)NODES * 64 * 2);
    float* as1    = (float*)alloc((size_t)NODES * HEADS * 4);
    float* ad1    = (float*)alloc((size_t)NODES * HEADS * 4);
    float* as2    = (float*)alloc((size_t)NODES * 4);
    float* ad2    = (float*)alloc((size_t)NODES * 4);
    int* rowptr   = (int*)alloc((size_t)NODES * 4);
    int* degarr   = (int*)alloc((size_t)NODES * 4);
    int* col      = (int*)alloc((size_t)NBUCK * BCAP * 4);
    int* tmp      = (int*)alloc((size_t)NBUCK * BCAP * 4);
    unsigned short* w1t = (unsigned short*)alloc((size_t)FIN * C1 * 2);
    unsigned short* w2t = (unsigned short*)alloc((size_t)CLS * 128 * 2);
    int* bwp      = (int*)alloc((size_t)NBUCK * 4);

    const int GB1 = (NODES + 63) / 64;           // 782 gemm1 blocks
    const int GBA = (E + EPB - 1) / EPB;         // bucketA blocks

    k_prep<<<1, 256, 0, stream>>>(W1, W2, w1t, w2t, bwp);
    k_front<<<GB1 + GBA, 256, 0, stream>>>(x, w1t, aS1, aD1, h1b, as1, ad1,
                                           src, dst, E, bwp, tmp, GB1);
    k_bucketB<<<NBUCK, 256, 0, stream>>>(bwp, tmp, col, rowptr, degarr);
    k_agg1<<<(NODES * 64) / 256, 256, 0, stream>>>(h1b, as1, ad1, rowptr, degarr,
                                                   col, b1, out1);
    k_gemm2<<<(NODES + 63) / 64, 256, 0, stream>>>(out1, w2t, aS2, aD2, h2b, as2, ad2);
    k_agg2<<<(NODES * 64) / 256, 256, 0, stream>>>(h2b, as2, ad2, rowptr, degarr,
                                                   col, b2, out);
}